// Round 15
// baseline (217.787 us; speedup 1.0000x reference)
//
#include <hip/hip_runtime.h>

typedef __attribute__((ext_vector_type(8)))  short short8;
typedef __attribute__((ext_vector_type(4)))  float f32x4;
typedef __attribute__((ext_vector_type(16))) float f32x16;
typedef __attribute__((ext_vector_type(2)))  unsigned uint2v;

constexpr int B  = 2;
constexpr int T  = 2048;
constexpr int C  = 1024;
constexpr int H  = 16;
constexpr int HD = 64;

// ---------------- helpers ----------------
__device__ inline unsigned bf16rne(float a){
  unsigned u = __builtin_bit_cast(unsigned, a);
  u += 0x7fffu + ((u >> 16) & 1u);
  return u >> 16;
}
__device__ inline unsigned bf16pair(float a, float b){
  unsigned ua = __builtin_bit_cast(unsigned, a); ua += 0x7fffu + ((ua >> 16) & 1u);
  unsigned ub = __builtin_bit_cast(unsigned, b); ub += 0x7fffu + ((ub >> 16) & 1u);
  return (ua >> 16) | (ub & 0xffff0000u);
}
__device__ inline void gll16(const void* g, void* l){
  __builtin_amdgcn_global_load_lds(
      (const __attribute__((address_space(1))) unsigned*)g,
      (__attribute__((address_space(3))) unsigned*)l, 16, 0, 0);
}
__device__ inline float exp2f_(float x){
#if __has_builtin(__builtin_amdgcn_exp2f)
  return __builtin_amdgcn_exp2f(x);
#else
  return __builtin_exp2f(x);
#endif
}
__device__ inline unsigned cvtpk(float lo, float hi){
  unsigned r;
  asm("v_cvt_pk_bf16_f32 %0, %1, %2" : "=v"(r) : "v"(lo), "v"(hi));
  return r;
}

// ---------------- fp32 -> bf16 convert: WEIGHTS ONLY (16 MB traffic) --------
__global__ void convert_w(const float* __restrict__ ipw, const float* __restrict__ opw,
                          unsigned* __restrict__ dst)
{
  const int i = blockIdx.x * 256 + threadIdx.x;
  const long e = (long)i * 8;
  const float* src; long off;
  if (e < 3145728) { src = ipw; off = e; }
  else             { src = opw; off = e - 3145728; }
  const float4 x0 = *(const float4*)(src + off);
  const float4 x1 = *(const float4*)(src + off + 4);
  uint4 st;
  st.x = bf16pair(x0.x, x0.y); st.y = bf16pair(x0.z, x0.w);
  st.z = bf16pair(x1.x, x1.y); st.w = bf16pair(x1.z, x1.w);
  *(uint4*)(dst + (size_t)i*4) = st;
}

// ---------------- QKV GEMM: 128x128, BK=64, fp32-A-in-LDS fusion ------------
// r10-r13 lesson: reg-staging the A conversion (load->pack->ds_write) has
// unhideable latency — every sync structure landed at 58-64 us. This keeps
// r9's PROVEN gll16 2-barrier staging for BOTH operands; A goes into LDS as
// RAW fp32 (32 KB buffer) and is converted on the LDS->reg fragment read
// with v_cvt_pk_bf16_f32 (1 op per pair, RNE — matches bf16rne).
// A-swizzle re-derived at 32B-chunk granularity (row = 256 B = 8 chunks):
//   stage: lane s in row r sources global subchunk ((s>>1)^(r&7))*2+(s&1)
//   read:  fragment chunk g reads LDS chunk g^(r&7)   [same involution]
// W-path byte-identical to r9. Epilogue byte-identical to r9/r14.
// LDS 48 KB -> still 3 blocks/CU at (256,3).
__global__ __launch_bounds__(256, 3) void gemm_qkv(
    const float* __restrict__ A0, const float* __restrict__ A1,
    const float* __restrict__ A2,
    const unsigned short* __restrict__ Wb, const float* __restrict__ bias,
    unsigned short* __restrict__ Qb, unsigned short* __restrict__ Kf,
    unsigned short* __restrict__ Vf)
{
  __shared__ __align__(16) char gsm[49152];   // As fp32 32K + Bs bf16 16K; epi Ls 18.4K
  float*          Asf = (float*)gsm;                    // [128][64] fp32, 32B-chunk swizzled
  unsigned short* Bs  = (unsigned short*)(gsm + 32768); // [128][64] bf16 swizzled

  const int tid  = threadIdx.x, lane = tid & 63, wv = tid >> 6;
  const int wm   = wv & 1, wn = wv >> 1;
  const int bm   = blockIdx.x, bn = blockIdx.y;   // x=bm: XCD = bm%8 (A-locality)
  const int m16  = lane & 15, quad = lane >> 4;

  const int which = bn >> 3;
  const float* A = (which == 0) ? A0 : (which == 1 ? A1 : A2);

  f32x4 acc[4][4];
#pragma unroll
  for (int i = 0; i < 4; i++)
#pragma unroll
    for (int j = 0; j < 4; j++) acc[i][j] = (f32x4){0.f, 0.f, 0.f, 0.f};

  // A staging (fp32): wave wv covers rows wv*32 .. +31 via 8 gll16 (4 rows each)
  const int rlA = lane >> 4;          // row-in-group 0..3
  const int sA  = lane & 15;          // 16B subchunk 0..15
  // W staging (bf16): r9-identical
  const int srowW = wv * 32 + (lane >> 3);
  const int skpW  = (((lane & 7) ^ (lane >> 3))) * 8;
  const int xr    = m16 & 7;          // read-side row&7 (rows stride 8/16 keep low bits)

  for (int k0 = 0; k0 < 1024; k0 += 64) {
    __syncthreads();
#pragma unroll
    for (int g = 0; g < 8; g++) {
      const int row = wv*32 + g*4 + rlA;
      const int se  = (((sA >> 1) ^ ((g & 1)*4 + rlA)) << 3) + ((sA & 1) << 2);
      gll16(A + (size_t)(bm*128 + row)*1024 + k0 + se, (char*)Asf + wv*8192 + g*1024);
    }
#pragma unroll
    for (int p = 0; p < 4; p++)
      gll16(Wb + (size_t)(bn*128 + srowW + p*8)*1024 + k0 + skpW, (char*)Bs + wv*4096 + p*1024);
    __syncthreads();

#pragma unroll
    for (int kk = 0; kk < 2; kk++) {
      const int gch = kk*4 + quad;
      const int chA = (gch ^ xr) * 32;   // fp32 row: 8 chunks x 32 B
      const int chW = (gch ^ xr) * 16;   // bf16 row: 8 chunks x 16 B
      short8 af[4], bf[4];
#pragma unroll
      for (int i = 0; i < 4; i++) {
        const char* pa = (const char*)Asf + (wm*64 + i*16 + m16)*256 + chA;
        const f32x4 lo = *(const f32x4*)pa;
        const f32x4 hi = *(const f32x4*)(pa + 16);
        union { unsigned u[4]; short8 v; } P;
        P.u[0] = cvtpk(lo[0], lo[1]);
        P.u[1] = cvtpk(lo[2], lo[3]);
        P.u[2] = cvtpk(hi[0], hi[1]);
        P.u[3] = cvtpk(hi[2], hi[3]);
        af[i] = P.v;
      }
#pragma unroll
      for (int j = 0; j < 4; j++)
        bf[j] = *(const short8*)((const char*)Bs + (wn*64 + j*16 + m16)*128 + chW);
#pragma unroll
      for (int i = 0; i < 4; i++)
#pragma unroll
        for (int j = 0; j < 4; j++)
          acc[i][j] = __builtin_amdgcn_mfma_f32_16x16x32_bf16(af[i], bf[j], acc[i][j], 0,0,0);
    }
  }

  __syncthreads();
  float* Ls = (float*)gsm;
  const int hbase = (bn & 7) * 2;
  const int b = bm >> 4;
  const int tbase = (bm & 15) * 128;
  const float ksc = (which == 1) ? 0.18033688f : 1.0f;   // 0.125 * log2(e)

  if (which < 2) {
#pragma unroll
    for (int j = 0; j < 4; ++j) {
      const float bj = bias[bn*128 + wn*64 + j*16 + m16] * ksc;
#pragma unroll
      for (int i = 0; i < 4; ++i) {
        const int m0 = wm*64 + i*16 + quad*4;
#pragma unroll
        for (int r = 0; r < 4; ++r)
          Ls[(m0 + r)*36 + wn*16 + m16] = __builtin_fmaf(acc[i][j][r], ksc, bj);
      }
      __syncthreads();
#pragma unroll
      for (int r2 = 0; r2 < 2; ++r2) {
        const int v = r2*256 + tid;
        const int m = v & 127, seg = v >> 7;
        const int wn2 = seg >> 1;
        const float* src = &Ls[m*36 + wn2*16 + (seg & 1)*8];
        const float4 f0 = *(const float4*)src;
        const float4 f1 = *(const float4*)(src + 4);
        uint4 st;
        st.x = bf16pair(f0.x, f0.y); st.y = bf16pair(f0.z, f0.w);
        st.z = bf16pair(f1.x, f1.y); st.w = bf16pair(f1.z, f1.w);
        const int bhh = b*16 + hbase + wn2;
        if (which == 0) {
          const int d0 = j*16 + (seg & 1)*8;
          *(uint4*)&Qb[((size_t)(bhh*2048) + tbase + m)*64 + d0] = st;
        } else {
          // K fragment-major: cell = ((bh*32+kt)*8 + s*2 + wk)*64 + h2*32 + ln
          const int kt = (tbase + m) >> 6;
          const int wkk = (m >> 5) & 1, ln2 = m & 31;
          const int h2 = seg & 1;               // s = j
          uint4* dp = (uint4*)Kf + ((size_t)(bhh*32 + kt)*8 + j*2 + wkk)*64 + h2*32 + ln2;
          *dp = st;
        }
      }
      __syncthreads();
    }
  } else {
#pragma unroll
    for (int j = 0; j < 4; ++j) {
      const float bj = bias[bn*128 + wn*64 + j*16 + m16];
      const int col = wn*16 + m16;
#pragma unroll
      for (int i = 0; i < 4; ++i) {
        f32x4 tv = acc[i][j];
        tv[0] += bj; tv[1] += bj; tv[2] += bj; tv[3] += bj;
        *(f32x4*)&Ls[col*132 + wm*64 + i*16 + quad*4] = tv;
      }
      __syncthreads();
#pragma unroll
      for (int r2 = 0; r2 < 2; ++r2) {
        const int v = r2*256 + tid;
        const int n = v >> 4, mseg = v & 15;
        const float* src = &Ls[n*132 + mseg*8];
        const float4 f0 = *(const float4*)src;
        const float4 f1 = *(const float4*)(src + 4);
        uint4 st;
        st.x = bf16pair(f0.x, f0.y); st.y = bf16pair(f0.z, f0.w);
        st.z = bf16pair(f1.x, f1.y); st.w = bf16pair(f1.z, f1.w);
        const int d = j*16 + (n & 15);
        const int bhh = b*16 + hbase + (n >> 4);
        const int t0 = tbase + mseg*8;
        // V fragment-major: cell = (((bh*32+kt)*2+dt)*2+c)*2+wk
        const int kt = t0 >> 6, tc = (t0 & 63) >> 3;
        const int wkk = tc >> 2, cc = (tc >> 1) & 1, h2 = tc & 1;
        const int dt = d >> 5, ln2 = d & 31;
        uint4* dp = (uint4*)Vf + (size_t)(bhh*32 + kt)*512 + dt*256 + cc*128 + wkk*64 + h2*32 + ln2;
        *dp = st;
      }
      __syncthreads();
    }
  }
}

// ---------------- out-proj GEMM: 64x64 tile, BK=64, swizzled LDS (r9) -------
__global__ __launch_bounds__(256, 4) void gemm_out(
    const unsigned short* __restrict__ Ab, const unsigned short* __restrict__ Wb,
    const float* __restrict__ bias, float* __restrict__ outF)
{
  __shared__ __align__(16) char gsm[16384];
  unsigned short* As = (unsigned short*)gsm;          // [64][64] swizzled
  unsigned short* Ws = (unsigned short*)(gsm + 8192); // [64][64] swizzled

  const int tid  = threadIdx.x, lane = tid & 63, wv = tid >> 6;
  const int bm   = blockIdx.x, bn = blockIdx.y;       // x=bm: 64, y=bn: 16
  const int m16  = lane & 15, quad = lane >> 4;

  f32x4 acc[4];
#pragma unroll
  for (int i = 0; i < 4; i++) acc[i] = (f32x4){0.f, 0.f, 0.f, 0.f};

  const int srow = wv * 16 + (lane >> 3);             // + p*8; row&7 = lane>>3
  const int skp  = (((lane & 7) ^ (lane >> 3))) * 8;  // pre-swizzled source chunk
  const int xr   = m16 & 7;

  for (int k0 = 0; k0 < 1024; k0 += 64) {
    __syncthreads();
#pragma unroll
    for (int p = 0; p < 2; p++) {
      gll16(Ab + (size_t)(bm*64 + srow + p*8)*1024 + k0 + skp, (char*)As + wv*2048 + p*1024);
      gll16(Wb + (size_t)(bn*64 + srow + p*8)*1024 + k0 + skp, (char*)Ws + wv*2048 + p*1024);
    }
    __syncthreads();

#pragma unroll
    for (int kk = 0; kk < 2; kk++) {
      const int ch = ((kk*4 + quad) ^ xr) * 16;
      short8 af[4], bf;
#pragma unroll
      for (int i = 0; i < 4; i++)
        af[i] = *(const short8*)((const char*)As + (i*16 + m16)*128 + ch);
      bf = *(const short8*)((const char*)Ws + (wv*16 + m16)*128 + ch);
#pragma unroll
      for (int i = 0; i < 4; i++)
        acc[i] = __builtin_amdgcn_mfma_f32_16x16x32_bf16(af[i], bf, acc[i], 0,0,0);
    }
  }

  const int n_e = bn*64 + wv*16 + m16;
  const float bj = bias[n_e];
#pragma unroll
  for (int i = 0; i < 4; i++) {
    const int mbase = bm*64 + i*16 + quad*4;
#pragma unroll
    for (int r = 0; r < 4; r++)
      outF[(size_t)(mbase + r) * 1024 + n_e] = acc[i][r] + bj;
  }
}

// ---------------- MFMA flash attention: LDS-free K-loop (round-4/7 verified)
// 51.2-51.5 us, VGPR 76, spill-free. Single dispatch (r8 split cost +2.9 us).
__global__ __launch_bounds__(256, 3) void attn_k(
    const unsigned short* __restrict__ Qb, const unsigned short* __restrict__ Kf,
    const unsigned short* __restrict__ Vf, const int* __restrict__ wptr,
    unsigned short* __restrict__ ctx)
{
  __shared__ __align__(16) char smem[16896];
  float* Om   = (float*)smem;          // 16 KB epilogue exchange
  float* lbuf = (float*)(smem + 16384);

  const int tid = threadIdx.x, lane = tid & 63, wv = tid >> 6;
  const int wq = wv >> 1, wk = wv & 1;
  const int h = lane >> 5, ln = lane & 31;
  const int bh = blockIdx.x, qt = blockIdx.y;
  const int win = *wptr;
  const int q0 = qt * 64 + wq * 32;
  const size_t hb = (size_t)bh * T * HD;

  constexpr float LOG2E = 1.44269504f;

  short8 qf[4];
#pragma unroll
  for (int s = 0; s < 4; s++)
    qf[s] = *(const short8*)(Qb + hb + (size_t)(q0 + ln)*64 + s*16 + h*8);

  short8 onesv;
#pragma unroll
  for (int jj = 0; jj < 8; jj++) onesv[jj] = (short)0x3F80;

  f32x16 O0, O1, Lacc, Zv;
#pragma unroll
  for (int r = 0; r < 16; r++) { O0[r] = 0.f; O1[r] = 0.f; Lacc[r] = 0.f; Zv[r] = 0.f; }
  const int tq = q0 + ln;

  const uint4* kbase = (const uint4*)Kf + (size_t)bh*32*512 + wk*64 + lane;
  const uint4* vbase = (const uint4*)Vf + (size_t)bh*32*512 + wk*64 + lane;

  uint4 kA[4], vA[4];
#pragma unroll
  for (int s = 0; s < 4; s++) kA[s] = kbase[s*128];
#pragma unroll
  for (int u = 0; u < 4; u++) vA[u] = vbase[(u >> 1)*256 + (u & 1)*128];  // u = dt*2+c

  for (int kt = 0; kt < 32; ++kt) {
    // S^T = K·Q^T
    f32x16 st;
#pragma unroll
    for (int s = 0; s < 4; s++) {
      const short8 kf2 = __builtin_bit_cast(short8, kA[s]);
      st = __builtin_amdgcn_mfma_f32_32x32x16_bf16(kf2, qf[s], (s == 0 ? Zv : st), 0, 0, 0);
    }
    // prefetch next K (kA regs free after S) — covered by exp+PV latency
    if (kt < 31) {
      const size_t o = (size_t)(kt + 1) * 512;
#pragma unroll
      for (int s = 0; s < 4; s++) kA[s] = kbase[o + s*128];
    }

    const int kb = kt*64 + wk*32;
    int sep = 0;
    if (kb > q0 + 31) sep = kb - (q0 + 31);
    else if (q0 > kb + 31) sep = q0 - (kb + 31);
    const int d1 = kb + 31 - q0, d2 = q0 + 31 - kb;
    const int dmax = max(d1 < 0 ? -d1 : d1, d2 < 0 ? -d2 : d2);

    float pr[16];
    if (sep > win) {
#pragma unroll
      for (int r = 0; r < 16; r++) pr[r] = exp2f_(st[r]);
    } else if (dmax <= win) {
#pragma unroll
      for (int r = 0; r < 16; r++) pr[r] = exp2f_(st[r] + LOG2E);
    } else {
      const int tkb = kb + 4*h;
#pragma unroll
      for (int r = 0; r < 16; r++) {
        const int tk = tkb + (r & 3) + 8*(r >> 2);
        int dd = tq - tk; dd = dd < 0 ? -dd : dd;
        pr[r] = exp2f_(st[r] + (dd <= win ? LOG2E : 0.0f));
      }
    }

    unsigned pk[8];
#pragma unroll
    for (int g = 0; g < 8; g++)
      pk[g] = __builtin_amdgcn_perm(__builtin_bit_cast(unsigned, pr[2*g+1]),
                                    __builtin_bit_cast(unsigned, pr[2*g]),
                                    0x07060302u);

#pragma unroll
    for (int c = 0; c < 2; c++) {
      // lane[i]<->lane[i+32] exchange in one VALU op each
      const uint2v s02 = __builtin_amdgcn_permlane32_swap(pk[4*c+0], pk[4*c+2], false, false);
      const uint2v s13 = __builtin_amdgcn_permlane32_swap(pk[4*c+1], pk[4*c+3], false, false);
      union { unsigned u[4]; short8 v; } P;
      P.u[0] = s02[0];
      P.u[1] = s13[0];
      P.u[2] = s02[1];
      P.u[3] = s13[1];
#pragma unroll
      for (int dt = 0; dt < 2; dt++) {
        const short8 vf2 = __builtin_bit_cast(short8, vA[dt*2 + c]);
        if (dt == 0) O0 = __builtin_amdgcn_mfma_f32_32x32x16_bf16(P.v, vf2, O0, 0,0,0);
        else         O1 = __builtin_amdgcn_mfma_f32_32x32x16_bf16(P.v, vf2, O1, 0,0,0);
      }
      Lacc = __builtin_amdgcn_mfma_f32_32x32x16_bf16(P.v, onesv, Lacc, 0,0,0);
    }

    // prefetch next V (vA free after PV) — covered by next S+exp latency
    if (kt < 31) {
      const size_t o = (size_t)(kt + 1) * 512;
#pragma unroll
      for (int u = 0; u < 4; u++) vA[u] = vbase[o + (u >> 1)*256 + (u & 1)*128];
    }
  }

  __syncthreads();
  if (wk == 1) {
#pragma unroll
    for (int r = 0; r < 16; r++) {
      Om[wq*2048 + r*64 + lane]        = O0[r];
      Om[wq*2048 + (16 + r)*64 + lane] = O1[r];
    }
    if (ln == 0) {
#pragma unroll
      for (int r = 0; r < 16; r++)
        lbuf[wq*32 + (r & 3) + 8*(r >> 2) + 4*h] = Lacc[r];
    }
  }
  __syncthreads();
  if (wk == 0) {
    const int b = bh >> 4, hh = bh & 15;
#pragma unroll
    for (int r = 0; r < 16; r++) {
      const int qrow = (r & 3) + 8*(r >> 2) + 4*h;
      const float lt = Lacc[r] + lbuf[wq*32 + qrow];
      const float linv = 1.0f / lt;
      const int t = q0 + qrow;
      const float o0 = (O0[r] + Om[wq*2048 + r*64 + lane]) * linv;
      const float o1 = (O1[r] + Om[wq*2048 + (16 + r)*64 + lane]) * linv;
      unsigned short* cp = ctx + (size_t)(b*2048 + t)*1024 + hh*64;
      cp[ln]      = (unsigned short)bf16rne(o0);
      cp[32 + ln] = (unsigned short)bf16rne(o1);
    }
  }
}

// ---------------- launch ----------------
extern "C" void kernel_launch(void* const* d_in, const int* in_sizes, int n_in,
                              void* d_out, int out_size, void* d_ws, size_t ws_size,
                              hipStream_t stream)
{
  const float* query = (const float*)d_in[0];
  const float* key   = (const float*)d_in[1];
  const float* value = (const float*)d_in[2];
  const float* ipw   = (const float*)d_in[3];
  const float* ipb   = (const float*)d_in[4];
  const float* opw   = (const float*)d_in[5];
  const float* opb   = (const float*)d_in[6];
  const int*   win   = (const int*)d_in[7];

  char* ws = (char*)d_ws;
  unsigned short* Winbf  = (unsigned short*)(ws);             // 3072*1024 bf16
  unsigned short* Woutbf = (unsigned short*)(ws + 6291456);   // 1024*1024 bf16
  unsigned short* Qb     = (unsigned short*)(ws + 33554432);  // [b,h,t,d]
  unsigned short* Kf     = (unsigned short*)(ws + 41943040);  // fragment-major, pre-scaled
  unsigned short* Vf     = (unsigned short*)(ws + 50331648);  // fragment-major
  unsigned short* ctx    = (unsigned short*)(ws + 58720256);  // [4096][1024]

  convert_w<<<2048, 256, 0, stream>>>(ipw, opw, (unsigned*)ws);

  gemm_qkv<<<dim3(32, 24), 256, 0, stream>>>(
      query, key, value, Winbf, ipb, Qb, Kf, Vf);

  attn_k<<<dim3(32, 32), 256, 0, stream>>>(Qb, Kf, Vf, win, ctx);

  gemm_out<<<dim3(64, 16), 256, 0, stream>>>(
      ctx, Woutbf, opb, (float*)d_out);
}

// Round 16
// 205.234 us; speedup vs baseline: 1.0612x; 1.0612x over previous
//
#include <hip/hip_runtime.h>

typedef __attribute__((ext_vector_type(8)))  short short8;
typedef __attribute__((ext_vector_type(4)))  float f32x4;
typedef __attribute__((ext_vector_type(16))) float f32x16;
typedef __attribute__((ext_vector_type(2)))  unsigned uint2v;

constexpr int B  = 2;
constexpr int T  = 2048;
constexpr int C  = 1024;
constexpr int H  = 16;
constexpr int HD = 64;

// ---------------- helpers ----------------
__device__ inline unsigned bf16rne(float a){
  unsigned u = __builtin_bit_cast(unsigned, a);
  u += 0x7fffu + ((u >> 16) & 1u);
  return u >> 16;
}
__device__ inline unsigned bf16pair(float a, float b){
  unsigned ua = __builtin_bit_cast(unsigned, a); ua += 0x7fffu + ((ua >> 16) & 1u);
  unsigned ub = __builtin_bit_cast(unsigned, b); ub += 0x7fffu + ((ub >> 16) & 1u);
  return (ua >> 16) | (ub & 0xffff0000u);
}
__device__ inline void gll16(const void* g, void* l){
  __builtin_amdgcn_global_load_lds(
      (const __attribute__((address_space(1))) unsigned*)g,
      (__attribute__((address_space(3))) unsigned*)l, 16, 0, 0);
}
__device__ inline float exp2f_(float x){
#if __has_builtin(__builtin_amdgcn_exp2f)
  return __builtin_amdgcn_exp2f(x);
#else
  return __builtin_exp2f(x);
#endif
}

// ---------------- fp32 -> bf16 convert: weights + qkv inputs (96 MB) --------
__global__ void convert_k(const float* __restrict__ ipw, const float* __restrict__ opw,
                          const float* __restrict__ q, const float* __restrict__ k,
                          const float* __restrict__ v, unsigned* __restrict__ dst)
{
  const int i = blockIdx.x * 256 + threadIdx.x;
  const long e = (long)i * 8;
  const float* src; long off;
  if      (e <  3145728) { src = ipw; off = e; }
  else if (e <  4194304) { src = opw; off = e - 3145728; }
  else if (e <  8388608) { src = q;   off = e - 4194304; }
  else if (e < 12582912) { src = k;   off = e - 8388608; }
  else                   { src = v;   off = e - 12582912; }
  const float4 x0 = *(const float4*)(src + off);
  const float4 x1 = *(const float4*)(src + off + 4);
  uint4 st;
  st.x = bf16pair(x0.x, x0.y); st.y = bf16pair(x0.z, x0.w);
  st.z = bf16pair(x1.x, x1.y); st.w = bf16pair(x1.z, x1.w);
  *(uint4*)(dst + (size_t)i*4) = st;
}

// ---------------- QKV GEMM: 128x128, BK=64, dbuf + COUNTED vmcnt (T3/T4) ----
// r10-r15: five fused-A variants all ~58 us because the vmem queue drains at
// (or effectively at) every barrier. This is the m201-proven pattern done
// properly: per iter — s_waitcnt vmcnt(8) (next tile's 8 gll16 stay IN
// FLIGHT across the barrier, never drained to 0) -> raw s_barrier -> MFMA
// tile k -> raw s_barrier -> issue tile k+2. Per-wave vmcnt before barrier1
// publishes that wave's loads to the group (m201 semantics).
// Staging/fragment path byte-identical to r9 (harness-verified): bf16 A+W
// gll16, both-sides chunk swizzle, x=bm grid (XCD=bm%8).
// LDS 64 KB (2x16K A + 2x16K W) -> 2 blocks/CU; fine, latency now hides
// WITHIN the block. launch_bounds(256,2) -> 256-reg budget, no spill.
__global__ __launch_bounds__(256, 2) void gemm_qkv(
    const unsigned short* __restrict__ A0, const unsigned short* __restrict__ A1,
    const unsigned short* __restrict__ A2,
    const unsigned short* __restrict__ Wb, const float* __restrict__ bias,
    unsigned short* __restrict__ Qb, unsigned short* __restrict__ Kf,
    unsigned short* __restrict__ Vf)
{
  __shared__ __align__(16) char gsm[65536];   // As[2]16K + Bs[2]16K; epi Ls 18.4K
  const int tid  = threadIdx.x, lane = tid & 63, wv = tid >> 6;
  const int wm   = wv & 1, wn = wv >> 1;
  const int bm   = blockIdx.x, bn = blockIdx.y;   // x=bm: XCD = bm%8 (A-locality)
  const int m16  = lane & 15, quad = lane >> 4;

  const int which = bn >> 3;
  const unsigned short* A = (which == 0) ? A0 : (which == 1 ? A1 : A2);

  f32x4 acc[4][4];
#pragma unroll
  for (int i = 0; i < 4; i++)
#pragma unroll
    for (int j = 0; j < 4; j++) acc[i][j] = (f32x4){0.f, 0.f, 0.f, 0.f};

  const int srow = wv * 32 + (lane >> 3);             // + p*8; row&7 = lane>>3
  const int skp  = (((lane & 7) ^ (lane >> 3))) * 8;  // pre-swizzled source chunk
  const int xr   = m16 & 7;                           // read-side row&7

  // stage tile kt (K-cols kt*64..+63) into buffer b: 8 gll16
  auto stage = [&](int kt, int b){
    const int k0 = kt * 64;
#pragma unroll
    for (int p = 0; p < 4; p++) {
      gll16(A  + (size_t)(bm*128 + srow + p*8)*1024 + k0 + skp,
            (char*)gsm + b*16384 + wv*4096 + p*1024);
      gll16(Wb + (size_t)(bn*128 + srow + p*8)*1024 + k0 + skp,
            (char*)gsm + 32768 + b*16384 + wv*4096 + p*1024);
    }
  };

  stage(0, 0);
  stage(1, 1);

  for (int kt = 0; kt < 16; ++kt) {
    const int cur = kt & 1;
    // tile kt landed iff all but the newest 8 loads (tile kt+1) completed
    if (kt < 15) asm volatile("s_waitcnt vmcnt(8)" ::: "memory");
    else         asm volatile("s_waitcnt vmcnt(0)" ::: "memory");
    __builtin_amdgcn_sched_barrier(0);
    __builtin_amdgcn_s_barrier();           // publish: every wave's tile-kt loads landed
    __builtin_amdgcn_sched_barrier(0);

    const char* Asb = (const char*)gsm + cur*16384;
    const char* Bsb = (const char*)gsm + 32768 + cur*16384;
#pragma unroll
    for (int kk = 0; kk < 2; kk++) {
      const int ch = ((kk*4 + quad) ^ xr) * 16;   // swizzled chunk byte offset
      short8 af[4], bf[4];
#pragma unroll
      for (int i = 0; i < 4; i++)
        af[i] = *(const short8*)(Asb + (wm*64 + i*16 + m16)*128 + ch);
#pragma unroll
      for (int j = 0; j < 4; j++)
        bf[j] = *(const short8*)(Bsb + (wn*64 + j*16 + m16)*128 + ch);
#pragma unroll
      for (int i = 0; i < 4; i++)
#pragma unroll
        for (int j = 0; j < 4; j++)
          acc[i][j] = __builtin_amdgcn_mfma_f32_16x16x32_bf16(af[i], bf[j], acc[i][j], 0,0,0);
    }
    __builtin_amdgcn_sched_barrier(0);
    __builtin_amdgcn_s_barrier();           // everyone done reading buffer cur
    __builtin_amdgcn_sched_barrier(0);
    if (kt + 2 < 16) stage(kt + 2, cur);    // overwrite cur; in flight across next barrier
  }

  __syncthreads();
  float* Ls = (float*)gsm;
  const int hbase = (bn & 7) * 2;
  const int b = bm >> 4;
  const int tbase = (bm & 15) * 128;
  const float ksc = (which == 1) ? 0.18033688f : 1.0f;   // 0.125 * log2(e)

  if (which < 2) {
#pragma unroll
    for (int j = 0; j < 4; ++j) {
      const float bj = bias[bn*128 + wn*64 + j*16 + m16] * ksc;
#pragma unroll
      for (int i = 0; i < 4; ++i) {
        const int m0 = wm*64 + i*16 + quad*4;
#pragma unroll
        for (int r = 0; r < 4; ++r)
          Ls[(m0 + r)*36 + wn*16 + m16] = __builtin_fmaf(acc[i][j][r], ksc, bj);
      }
      __syncthreads();
#pragma unroll
      for (int r2 = 0; r2 < 2; ++r2) {
        const int v = r2*256 + tid;
        const int m = v & 127, seg = v >> 7;
        const int wn2 = seg >> 1;
        const float* src = &Ls[m*36 + wn2*16 + (seg & 1)*8];
        const float4 f0 = *(const float4*)src;
        const float4 f1 = *(const float4*)(src + 4);
        uint4 st;
        st.x = bf16pair(f0.x, f0.y); st.y = bf16pair(f0.z, f0.w);
        st.z = bf16pair(f1.x, f1.y); st.w = bf16pair(f1.z, f1.w);
        const int bhh = b*16 + hbase + wn2;
        if (which == 0) {
          const int d0 = j*16 + (seg & 1)*8;
          *(uint4*)&Qb[((size_t)(bhh*2048) + tbase + m)*64 + d0] = st;
        } else {
          // K fragment-major: cell = ((bh*32+kt)*8 + s*2 + wk)*64 + h2*32 + ln
          const int kt = (tbase + m) >> 6;
          const int wkk = (m >> 5) & 1, ln2 = m & 31;
          const int h2 = seg & 1;               // s = j
          uint4* dp = (uint4*)Kf + ((size_t)(bhh*32 + kt)*8 + j*2 + wkk)*64 + h2*32 + ln2;
          *dp = st;
        }
      }
      __syncthreads();
    }
  } else {
#pragma unroll
    for (int j = 0; j < 4; ++j) {
      const float bj = bias[bn*128 + wn*64 + j*16 + m16];
      const int col = wn*16 + m16;
#pragma unroll
      for (int i = 0; i < 4; ++i) {
        f32x4 tv = acc[i][j];
        tv[0] += bj; tv[1] += bj; tv[2] += bj; tv[3] += bj;
        *(f32x4*)&Ls[col*132 + wm*64 + i*16 + quad*4] = tv;
      }
      __syncthreads();
#pragma unroll
      for (int r2 = 0; r2 < 2; ++r2) {
        const int v = r2*256 + tid;
        const int n = v >> 4, mseg = v & 15;
        const float* src = &Ls[n*132 + mseg*8];
        const float4 f0 = *(const float4*)src;
        const float4 f1 = *(const float4*)(src + 4);
        uint4 st;
        st.x = bf16pair(f0.x, f0.y); st.y = bf16pair(f0.z, f0.w);
        st.z = bf16pair(f1.x, f1.y); st.w = bf16pair(f1.z, f1.w);
        const int d = j*16 + (n & 15);
        const int bhh = b*16 + hbase + (n >> 4);
        const int t0 = tbase + mseg*8;
        // V fragment-major: cell = (((bh*32+kt)*2+dt)*2+c)*2+wk
        const int kt = t0 >> 6, tc = (t0 & 63) >> 3;
        const int wkk = tc >> 2, cc = (tc >> 1) & 1, h2 = tc & 1;
        const int dt = d >> 5, ln2 = d & 31;
        uint4* dp = (uint4*)Vf + (size_t)(bhh*32 + kt)*512 + dt*256 + cc*128 + wkk*64 + h2*32 + ln2;
        *dp = st;
      }
      __syncthreads();
    }
  }
}

// ---------------- out-proj GEMM: 64x64, BK=64, dbuf + counted vmcnt ---------
// Same T3/T4 transformation; staging/fragment path byte-identical to r9.
// LDS 32 KB (2x8K + 2x8K) -> 4+ blocks/CU at (256,4).
__global__ __launch_bounds__(256, 4) void gemm_out(
    const unsigned short* __restrict__ Ab, const unsigned short* __restrict__ Wb,
    const float* __restrict__ bias, float* __restrict__ outF)
{
  __shared__ __align__(16) char gsm[32768];   // As[2]8K + Ws[2]8K
  const int tid  = threadIdx.x, lane = tid & 63, wv = tid >> 6;
  const int bm   = blockIdx.x, bn = blockIdx.y;       // x=bm: 64, y=bn: 16
  const int m16  = lane & 15, quad = lane >> 4;

  f32x4 acc[4];
#pragma unroll
  for (int i = 0; i < 4; i++) acc[i] = (f32x4){0.f, 0.f, 0.f, 0.f};

  const int srow = wv * 16 + (lane >> 3);             // + p*8; row&7 = lane>>3
  const int skp  = (((lane & 7) ^ (lane >> 3))) * 8;  // pre-swizzled source chunk
  const int xr   = m16 & 7;

  auto stage = [&](int kt, int b){
    const int k0 = kt * 64;
#pragma unroll
    for (int p = 0; p < 2; p++) {
      gll16(Ab + (size_t)(bm*64 + srow + p*8)*1024 + k0 + skp,
            (char*)gsm + b*8192 + wv*2048 + p*1024);
      gll16(Wb + (size_t)(bn*64 + srow + p*8)*1024 + k0 + skp,
            (char*)gsm + 16384 + b*8192 + wv*2048 + p*1024);
    }
  };

  stage(0, 0);
  stage(1, 1);

  for (int kt = 0; kt < 16; ++kt) {
    const int cur = kt & 1;
    if (kt < 15) asm volatile("s_waitcnt vmcnt(4)" ::: "memory");
    else         asm volatile("s_waitcnt vmcnt(0)" ::: "memory");
    __builtin_amdgcn_sched_barrier(0);
    __builtin_amdgcn_s_barrier();
    __builtin_amdgcn_sched_barrier(0);

    const char* Asb = (const char*)gsm + cur*8192;
    const char* Wsb = (const char*)gsm + 16384 + cur*8192;
#pragma unroll
    for (int kk = 0; kk < 2; kk++) {
      const int ch = ((kk*4 + quad) ^ xr) * 16;
      short8 af[4], bf;
#pragma unroll
      for (int i = 0; i < 4; i++)
        af[i] = *(const short8*)(Asb + (i*16 + m16)*128 + ch);
      bf = *(const short8*)(Wsb + (wv*16 + m16)*128 + ch);
#pragma unroll
      for (int i = 0; i < 4; i++)
        acc[i] = __builtin_amdgcn_mfma_f32_16x16x32_bf16(af[i], bf, acc[i], 0,0,0);
    }
    __builtin_amdgcn_sched_barrier(0);
    __builtin_amdgcn_s_barrier();
    __builtin_amdgcn_sched_barrier(0);
    if (kt + 2 < 16) stage(kt + 2, cur);
  }

  const int n_e = bn*64 + wv*16 + m16;
  const float bj = bias[n_e];
#pragma unroll
  for (int i = 0; i < 4; i++) {
    const int mbase = bm*64 + i*16 + quad*4;
#pragma unroll
    for (int r = 0; r < 4; r++)
      outF[(size_t)(mbase + r) * 1024 + n_e] = acc[i][r] + bj;
  }
}

// ---------------- MFMA flash attention: LDS-free K-loop (round-4/7 verified)
// 51.2-51.5 us, VGPR 76, spill-free. Single dispatch.
__global__ __launch_bounds__(256, 3) void attn_k(
    const unsigned short* __restrict__ Qb, const unsigned short* __restrict__ Kf,
    const unsigned short* __restrict__ Vf, const int* __restrict__ wptr,
    unsigned short* __restrict__ ctx)
{
  __shared__ __align__(16) char smem[16896];
  float* Om   = (float*)smem;          // 16 KB epilogue exchange
  float* lbuf = (float*)(smem + 16384);

  const int tid = threadIdx.x, lane = tid & 63, wv = tid >> 6;
  const int wq = wv >> 1, wk = wv & 1;
  const int h = lane >> 5, ln = lane & 31;
  const int bh = blockIdx.x, qt = blockIdx.y;
  const int win = *wptr;
  const int q0 = qt * 64 + wq * 32;
  const size_t hb = (size_t)bh * T * HD;

  constexpr float LOG2E = 1.44269504f;

  short8 qf[4];
#pragma unroll
  for (int s = 0; s < 4; s++)
    qf[s] = *(const short8*)(Qb + hb + (size_t)(q0 + ln)*64 + s*16 + h*8);

  short8 onesv;
#pragma unroll
  for (int jj = 0; jj < 8; jj++) onesv[jj] = (short)0x3F80;

  f32x16 O0, O1, Lacc, Zv;
#pragma unroll
  for (int r = 0; r < 16; r++) { O0[r] = 0.f; O1[r] = 0.f; Lacc[r] = 0.f; Zv[r] = 0.f; }
  const int tq = q0 + ln;

  const uint4* kbase = (const uint4*)Kf + (size_t)bh*32*512 + wk*64 + lane;
  const uint4* vbase = (const uint4*)Vf + (size_t)bh*32*512 + wk*64 + lane;

  uint4 kA[4], vA[4];
#pragma unroll
  for (int s = 0; s < 4; s++) kA[s] = kbase[s*128];
#pragma unroll
  for (int u = 0; u < 4; u++) vA[u] = vbase[(u >> 1)*256 + (u & 1)*128];  // u = dt*2+c

  for (int kt = 0; kt < 32; ++kt) {
    // S^T = K·Q^T
    f32x16 st;
#pragma unroll
    for (int s = 0; s < 4; s++) {
      const short8 kf2 = __builtin_bit_cast(short8, kA[s]);
      st = __builtin_amdgcn_mfma_f32_32x32x16_bf16(kf2, qf[s], (s == 0 ? Zv : st), 0, 0, 0);
    }
    // prefetch next K (kA regs free after S) — covered by exp+PV latency
    if (kt < 31) {
      const size_t o = (size_t)(kt + 1) * 512;
#pragma unroll
      for (int s = 0; s < 4; s++) kA[s] = kbase[o + s*128];
    }

    const int kb = kt*64 + wk*32;
    int sep = 0;
    if (kb > q0 + 31) sep = kb - (q0 + 31);
    else if (q0 > kb + 31) sep = q0 - (kb + 31);
    const int d1 = kb + 31 - q0, d2 = q0 + 31 - kb;
    const int dmax = max(d1 < 0 ? -d1 : d1, d2 < 0 ? -d2 : d2);

    float pr[16];
    if (sep > win) {
#pragma unroll
      for (int r = 0; r < 16; r++) pr[r] = exp2f_(st[r]);
    } else if (dmax <= win) {
#pragma unroll
      for (int r = 0; r < 16; r++) pr[r] = exp2f_(st[r] + LOG2E);
    } else {
      const int tkb = kb + 4*h;
#pragma unroll
      for (int r = 0; r < 16; r++) {
        const int tk = tkb + (r & 3) + 8*(r >> 2);
        int dd = tq - tk; dd = dd < 0 ? -dd : dd;
        pr[r] = exp2f_(st[r] + (dd <= win ? LOG2E : 0.0f));
      }
    }

    unsigned pk[8];
#pragma unroll
    for (int g = 0; g < 8; g++)
      pk[g] = __builtin_amdgcn_perm(__builtin_bit_cast(unsigned, pr[2*g+1]),
                                    __builtin_bit_cast(unsigned, pr[2*g]),
                                    0x07060302u);

#pragma unroll
    for (int c = 0; c < 2; c++) {
      // lane[i]<->lane[i+32] exchange in one VALU op each
      const uint2v s02 = __builtin_amdgcn_permlane32_swap(pk[4*c+0], pk[4*c+2], false, false);
      const uint2v s13 = __builtin_amdgcn_permlane32_swap(pk[4*c+1], pk[4*c+3], false, false);
      union { unsigned u[4]; short8 v; } P;
      P.u[0] = s02[0];
      P.u[1] = s13[0];
      P.u[2] = s02[1];
      P.u[3] = s13[1];
#pragma unroll
      for (int dt = 0; dt < 2; dt++) {
        const short8 vf2 = __builtin_bit_cast(short8, vA[dt*2 + c]);
        if (dt == 0) O0 = __builtin_amdgcn_mfma_f32_32x32x16_bf16(P.v, vf2, O0, 0,0,0);
        else         O1 = __builtin_amdgcn_mfma_f32_32x32x16_bf16(P.v, vf2, O1, 0,0,0);
      }
      Lacc = __builtin_amdgcn_mfma_f32_32x32x16_bf16(P.v, onesv, Lacc, 0,0,0);
    }

    // prefetch next V (vA free after PV) — covered by next S+exp latency
    if (kt < 31) {
      const size_t o = (size_t)(kt + 1) * 512;
#pragma unroll
      for (int u = 0; u < 4; u++) vA[u] = vbase[o + (u >> 1)*256 + (u & 1)*128];
    }
  }

  __syncthreads();
  if (wk == 1) {
#pragma unroll
    for (int r = 0; r < 16; r++) {
      Om[wq*2048 + r*64 + lane]        = O0[r];
      Om[wq*2048 + (16 + r)*64 + lane] = O1[r];
    }
    if (ln == 0) {
#pragma unroll
      for (int r = 0; r < 16; r++)
        lbuf[wq*32 + (r & 3) + 8*(r >> 2) + 4*h] = Lacc[r];
    }
  }
  __syncthreads();
  if (wk == 0) {
    const int b = bh >> 4, hh = bh & 15;
#pragma unroll
    for (int r = 0; r < 16; r++) {
      const int qrow = (r & 3) + 8*(r >> 2) + 4*h;
      const float lt = Lacc[r] + lbuf[wq*32 + qrow];
      const float linv = 1.0f / lt;
      const int t = q0 + qrow;
      const float o0 = (O0[r] + Om[wq*2048 + r*64 + lane]) * linv;
      const float o1 = (O1[r] + Om[wq*2048 + (16 + r)*64 + lane]) * linv;
      unsigned short* cp = ctx + (size_t)(b*2048 + t)*1024 + hh*64;
      cp[ln]      = (unsigned short)bf16rne(o0);
      cp[32 + ln] = (unsigned short)bf16rne(o1);
    }
  }
}

// ---------------- launch ----------------
extern "C" void kernel_launch(void* const* d_in, const int* in_sizes, int n_in,
                              void* d_out, int out_size, void* d_ws, size_t ws_size,
                              hipStream_t stream)
{
  const float* query = (const float*)d_in[0];
  const float* key   = (const float*)d_in[1];
  const float* value = (const float*)d_in[2];
  const float* ipw   = (const float*)d_in[3];
  const float* ipb   = (const float*)d_in[4];
  const float* opw   = (const float*)d_in[5];
  const float* opb   = (const float*)d_in[6];
  const int*   win   = (const int*)d_in[7];

  char* ws = (char*)d_ws;
  unsigned short* Winbf  = (unsigned short*)(ws);             // 3072*1024 bf16
  unsigned short* Woutbf = (unsigned short*)(ws + 6291456);   // 1024*1024 bf16
  unsigned short* Qin    = (unsigned short*)(ws + 8388608);   // [4096,1024] bf16
  unsigned short* Kin    = (unsigned short*)(ws + 16777216);
  unsigned short* Vin    = (unsigned short*)(ws + 25165824);
  unsigned short* Qb     = (unsigned short*)(ws + 33554432);  // [b,h,t,d]
  unsigned short* Kf     = (unsigned short*)(ws + 41943040);  // fragment-major, pre-scaled
  unsigned short* Vf     = (unsigned short*)(ws + 50331648);  // fragment-major
  unsigned short* ctx    = (unsigned short*)(ws + 58720256);  // [4096][1024]

  convert_k<<<8192, 256, 0, stream>>>(ipw, opw, query, key, value, (unsigned*)ws);

  gemm_qkv<<<dim3(32, 24), 256, 0, stream>>>(
      Qin, Kin, Vin, Winbf, ipb, Qb, Kf, Vf);

  attn_k<<<dim3(32, 32), 256, 0, stream>>>(Qb, Kf, Vf, win, ctx);

  gemm_out<<<dim3(64, 16), 256, 0, stream>>>(
      ctx, Woutbf, opb, (float*)d_out);
}